// Round 1
// 5249.895 us; speedup vs baseline: 1.1421x; 1.1421x over previous
//
#include <hip/hip_runtime.h>

// Coattention: B=32, Lq=Ld=1024, H=1024, fp32.
//   A  = q @ d^T                       [B, L, L]
//   P_d[q,dd] = softmax over dd (mask dd>=d_len)   (== ad^T)
//   P_q[q,dd] = softmax over q  (mask q>=q_len)    (== aq)
//   out2 sq^T = P_d   @ d      [B, L, H]
//   out3 sd^T = P_q^T @ q      [B, L, H]
//   out1 cd^T = P_q^T @ sq^T   [B, L, H]
// P is never materialized: GEMMs normalize A on the fly from per-row stats.
//
// This version: 128x128 block tile, 8x8 microtile per thread (64 FMA : 4
// ds_read_b128 per k-step), XOR-swizzled unpadded LDS (conflict-free b128
// fragment reads, <=2-way staging writes), register-prefetch double buffer
// with ONE __syncthreads per BK=16 k-tile.

constexpr int BATCH = 32;
constexpr int L  = 1024;  // Lq == Ld
constexpr int HD = 1024;

constexpr int BM = 128, BN = 128, BK = 16;
constexpr int NT = L / BK;  // 64 k-tiles (HD == L)

// XOR swizzle: column-bit4 ^= k-bit2, column-bit3 ^= k-bit3.
// Keeps 16B alignment (mask is a multiple of 4 floats), makes transpose-
// staging scalar writes 2-way (free) and fragment b128 reads conflict-free.
__device__ __forceinline__ int swzmask(int k) {
  return ((k & 4) << 2) | (k & 8);
}

// MODE 0: affinity  C = q @ d^T         (A-op: q rows [m][k], B-op: d rows [n][k])
// MODE 1: C = P_d @ B,  P_d[row,k] = exp(A[row][k]-m[row])/s[row], mask k>=len
// MODE 2: C = P^T @ B,  P^T[row,k] = exp(A[k][row]-m[row])/s[row], mask k>=len
template <int MODE>
__global__ __launch_bounds__(256) void gemm_kernel(
    const float* __restrict__ Asrc, const float* __restrict__ Bsrc,
    const float* __restrict__ m_arr, const float* __restrict__ s_arr,
    const int* __restrict__ len_arr, float* __restrict__ C) {
  __shared__ float As[2][BK][BM];   // 16 KB
  __shared__ float Bs[2][BK][BN];   // 16 KB

  const int b  = blockIdx.z;
  const int m0 = blockIdx.y * BM;
  const int n0 = blockIdx.x * BN;
  const int tid = (int)threadIdx.x;
  const int tx = tid & 15, ty = tid >> 4;

  const int len = (MODE == 0) ? L : len_arr[b];

  // Transpose-staging geometry (source is [row][k], k fast): 2 rows, 4 k each.
  const int sr = tid >> 2;          // 0..63
  const int sk = (tid & 3) << 2;    // 0,4,8,12
  // Direct-staging geometry (source is [k][col], col fast): 2 k-rows, 4 cols.
  const int kd = tid >> 5;          // 0..7
  const int c4 = (tid & 31) << 2;   // 0..124

  const float* aR0 = nullptr; const float* aR1 = nullptr;
  const float* aCol = nullptr;
  float mA0 = 0.f, mA1 = 0.f;
  float4 mCol = make_float4(0.f, 0.f, 0.f, 0.f);

  if (MODE == 0) {
    aR0 = Asrc + (size_t)b * L * HD + (size_t)(m0 + sr) * HD;
    aR1 = aR0 + (size_t)64 * HD;
  } else if (MODE == 1) {
    aR0 = Asrc + (size_t)b * L * L + (size_t)(m0 + sr) * L;
    aR1 = aR0 + (size_t)64 * L;
    mA0 = m_arr[b * L + m0 + sr];
    mA1 = m_arr[b * L + m0 + sr + 64];
  } else {
    aCol = Asrc + (size_t)b * L * L + m0 + c4;          // + k*L
    mCol = *(const float4*)(m_arr + b * L + m0 + c4);   // per-column max
  }

  const float* bR0 = nullptr; const float* bR1 = nullptr;
  const float* bCol = nullptr;
  if (MODE == 0) {
    bR0 = Bsrc + (size_t)b * L * HD + (size_t)(n0 + sr) * HD;
    bR1 = bR0 + (size_t)64 * HD;
  } else {
    bCol = Bsrc + (size_t)b * L * HD + n0 + c4;         // + k*HD
  }

  float4 va0, va1, vb0, vb1;  // prefetch registers

  auto loadTiles = [&](int k0) {
    if (MODE == 2) {
      va0 = *(const float4*)(aCol + (size_t)(k0 + kd) * L);
      va1 = *(const float4*)(aCol + (size_t)(k0 + kd + 8) * L);
    } else {
      va0 = *(const float4*)(aR0 + k0 + sk);
      va1 = *(const float4*)(aR1 + k0 + sk);
    }
    if (MODE == 0) {
      vb0 = *(const float4*)(bR0 + k0 + sk);
      vb1 = *(const float4*)(bR1 + k0 + sk);
    } else {
      vb0 = *(const float4*)(bCol + (size_t)(k0 + kd) * HD);
      vb1 = *(const float4*)(bCol + (size_t)(k0 + kd + 8) * HD);
    }
  };

  auto writeTiles = [&](int buf, int k0) {
    float (*as)[BM] = As[buf];
    float (*bs)[BN] = Bs[buf];
    if (MODE == 2) {
#pragma unroll
      for (int j = 0; j < 2; ++j) {
        const int k = kd + j * 8;
        const float4 v = j ? va1 : va0;
        const bool ok = (k0 + k) < len;
        float4 e;
        e.x = ok ? __expf(v.x - mCol.x) : 0.f;
        e.y = ok ? __expf(v.y - mCol.y) : 0.f;
        e.z = ok ? __expf(v.z - mCol.z) : 0.f;
        e.w = ok ? __expf(v.w - mCol.w) : 0.f;
        *(float4*)&as[k][c4 ^ swzmask(k)] = e;
      }
    } else if (MODE == 1) {
#pragma unroll
      for (int i = 0; i < 4; ++i) {
        const int k = sk + i;
        const bool ok = (k0 + k) < len;
        const int c = sr ^ swzmask(k);
        as[k][c]      = ok ? __expf(((const float*)&va0)[i] - mA0) : 0.f;
        as[k][c + 64] = ok ? __expf(((const float*)&va1)[i] - mA1) : 0.f;
      }
    } else {
#pragma unroll
      for (int i = 0; i < 4; ++i) {
        const int k = sk + i;
        const int c = sr ^ swzmask(k);
        as[k][c]      = ((const float*)&va0)[i];
        as[k][c + 64] = ((const float*)&va1)[i];
      }
    }
    if (MODE == 0) {
#pragma unroll
      for (int i = 0; i < 4; ++i) {
        const int k = sk + i;
        const int c = sr ^ swzmask(k);
        bs[k][c]      = ((const float*)&vb0)[i];
        bs[k][c + 64] = ((const float*)&vb1)[i];
      }
    } else {
#pragma unroll
      for (int j = 0; j < 2; ++j) {
        const int k = kd + j * 8;
        const float4 v = j ? vb1 : vb0;
        *(float4*)&bs[k][c4 ^ swzmask(k)] = v;
      }
    }
  };

  float acc[8][8] = {};

  loadTiles(0);
  writeTiles(0, 0);
  __syncthreads();

  int cur = 0;
  for (int t = 0; t < NT; ++t) {
    const bool more = (t + 1 < NT);
    if (more) loadTiles((t + 1) * BK);   // issue global loads early

    const float (*as)[BM] = As[cur];
    const float (*bs)[BN] = Bs[cur];
#pragma unroll
    for (int k = 0; k < BK; ++k) {
      const int msk = swzmask(k);
      const int ca = (ty << 2) ^ msk;
      const int cb = (tx << 2) ^ msk;
      const float4 a0 = *(const float4*)&as[k][ca];
      const float4 a1 = *(const float4*)&as[k][ca + 64];
      const float4 b0 = *(const float4*)&bs[k][cb];
      const float4 b1 = *(const float4*)&bs[k][cb + 64];
      const float a[8]  = {a0.x, a0.y, a0.z, a0.w, a1.x, a1.y, a1.z, a1.w};
      const float bb[8] = {b0.x, b0.y, b0.z, b0.w, b1.x, b1.y, b1.z, b1.w};
#pragma unroll
      for (int i = 0; i < 8; ++i)
#pragma unroll
        for (int j = 0; j < 8; ++j) acc[i][j] += a[i] * bb[j];
    }
    if (more) writeTiles(cur ^ 1, (t + 1) * BK);  // lands in the other buffer
    __syncthreads();                              // one barrier per k-tile
    cur ^= 1;
  }

  float* Cb = C + (size_t)b * L * HD;  // MODE 0: L*L == L*HD
#pragma unroll
  for (int ih = 0; ih < 2; ++ih) {
#pragma unroll
    for (int i = 0; i < 4; ++i) {
      const int row = m0 + ih * 64 + (ty << 2) + i;
      float sc = 1.f;
      if (MODE != 0) sc = 1.f / s_arr[b * L + row];
      const float* ar = acc[ih * 4 + i];
      const float4 v0 = make_float4(ar[0] * sc, ar[1] * sc, ar[2] * sc, ar[3] * sc);
      const float4 v1 = make_float4(ar[4] * sc, ar[5] * sc, ar[6] * sc, ar[7] * sc);
      float* cp = Cb + (size_t)row * HD + n0 + (tx << 2);
      *(float4*)cp = v0;
      *(float4*)(cp + 64) = v1;
    }
  }
}

// ------- Kernel 2: per-(b,q) max/sumexp over dd < d_len[b] (one wave per row) -------
__global__ __launch_bounds__(256) void row_stats_kernel(
    const float* __restrict__ A, const int* __restrict__ d_len,
    float* __restrict__ m_out, float* __restrict__ s_out) {
  const int wave = threadIdx.x / 64, lane = threadIdx.x % 64;
  const int row = blockIdx.x * 4 + wave;  // in [0, BATCH*L)
  const int b = row / L;
  const int len = d_len[b];
  const float* base = A + (size_t)row * L;
  float m = -1e30f;
  for (int k = lane; k < len; k += 64) m = fmaxf(m, base[k]);
#pragma unroll
  for (int off = 32; off > 0; off >>= 1) m = fmaxf(m, __shfl_xor(m, off, 64));
  float s = 0.f;
  for (int k = lane; k < len; k += 64) s += __expf(base[k] - m);
#pragma unroll
  for (int off = 32; off > 0; off >>= 1) s += __shfl_xor(s, off, 64);
  if (lane == 0) { m_out[row] = m; s_out[row] = s; }
}

// ------- Kernel 3: per-(b,dd) max/sumexp over q < q_len[b] (one thread per col) -------
__global__ __launch_bounds__(256) void col_stats_kernel(
    const float* __restrict__ A, const int* __restrict__ q_len,
    float* __restrict__ m_out, float* __restrict__ s_out) {
  const int col = blockIdx.x * 256 + threadIdx.x;  // in [0, BATCH*L)
  const int b = col / L, di = col % L;
  const int len = q_len[b];
  const float* base = A + (size_t)b * L * L + di;
  float m = -1e30f, s = 0.f;
  for (int k = 0; k < len; ++k) {
    const float v = base[(size_t)k * L];
    const float mn = fmaxf(m, v);
    s = s * __expf(m - mn) + __expf(v - mn);
    m = mn;
  }
  m_out[col] = m;
  s_out[col] = s;
}

extern "C" void kernel_launch(void* const* d_in, const int* in_sizes, int n_in,
                              void* d_out, int out_size, void* d_ws, size_t ws_size,
                              hipStream_t stream) {
  const float* q     = (const float*)d_in[0];
  const float* d     = (const float*)d_in[1];
  const int*   q_len = (const int*)d_in[2];
  const int*   d_len = (const int*)d_in[3];
  float* out = (float*)d_out;

  // workspace layout: A (B*L*L fp32), then 4 stats vectors (B*L fp32 each)
  float* A   = (float*)d_ws;
  const size_t aElems = (size_t)BATCH * L * L;
  float* m_d = A + aElems;
  float* s_d = m_d + (size_t)BATCH * L;
  float* m_q = s_d + (size_t)BATCH * L;
  float* s_q = m_q + (size_t)BATCH * L;

  dim3 gA(L / BN, L / BM, BATCH);
  gemm_kernel<0><<<gA, 256, 0, stream>>>(q, d, nullptr, nullptr, nullptr, A);

  row_stats_kernel<<<dim3(BATCH * L / 4), 256, 0, stream>>>(A, d_len, m_d, s_d);
  col_stats_kernel<<<dim3(BATCH * L / 256), 256, 0, stream>>>(A, q_len, m_q, s_q);

  float* cdT = out;                              // [B, L, HD]
  float* sqT = out + (size_t)BATCH * L * HD;     // [B, L, HD]
  float* sdT = sqT + (size_t)BATCH * L * HD;     // [B, L, HD]

  dim3 gN(HD / BN, L / BM, BATCH);
  // out2: sq^T = P_d @ d        (rows=q, k=dd, mask d_len)
  gemm_kernel<1><<<gN, 256, 0, stream>>>(A, d, m_d, s_d, d_len, sqT);
  // out3: sd^T = P_q^T @ q      (rows=dd, k=q, mask q_len)
  gemm_kernel<2><<<gN, 256, 0, stream>>>(A, q, m_q, s_q, q_len, sdT);
  // out1: cd^T = P_q^T @ sq^T   (same P, B = sq^T just written)
  gemm_kernel<2><<<gN, 256, 0, stream>>>(A, sqT, m_q, s_q, q_len, cdT);
}